// Round 13
// baseline (6013.843 us; speedup 1.0000x reference)
//
#include <hip/hip_runtime.h>

// FPS: 2 batches x 131072 pts, 4096 samples/batch, seed = point 0.
// EXACT certified lookahead FPS, v8 = r12 (3613us, PASSED) widened to
// KW=16 with a compact LDS layout. Code paths are r12 verbatim except:
//  (A) KW 8->16: extraction runs 16 pops (ship lanes 0..31); poll reads
//      16 quads/lane in ONE 16-load single-vmcnt batch; cutoff uses
//      rank-15 (same 128-slot read shape); R should halve (j tracks KW).
//  (B) compact mirror: 5 useful u32 per candidate ({keylo,keyhi,x,y}
//      written by even poll lanes, z by odd lanes - same registers,
//      same lane pairing as r12's 16B mirror) + u16 INDEX pool (sim
//      gathers coords via mirror[idx*5]). LDS ~45KB (fits; full-width
//      KW=16 mirror+pool would not).
//
// Evidence r0-r12: sys-scope rendezvous RT ~2.5us is the floor (sc0
// never resolves cross-CU, r0-r4). r12 ~= r6: per-round cost ~7us at
// j~8, R~512; sim_block and prune atomics were NOT the cost (r12's
// falsifier) => reduce R via deeper certified lookahead. r8's stale
// extraction and r10's coord-gather sim are known-bad; avoided.
//
// Per rendezvous round r (all 32 blocks of a batch):
//  1. EXTRACT per wave (exact dists, no barriers): 16 DPP-tournament
//     pops + winner-lane rescan with removal mask (r12 loop, c<16).
//     Lanes 2c/2c+1 capture pop-c into quads {keylo,keyhi,x,y}/{r,z,0,0}.
//     Key = dist_bits<<32 | r<<17 | (0x1FFFF - idx): u64 order ==
//     (dist desc, idx asc) == jnp.argmax first-index tiebreak.
//  2. SHIP: lanes 0..31 store 16B each, sys scope, unacked.
//  3. POLL: wave's 1024-quad quarter, 16 batched loads/lane (ONE vmcnt
//     RT), all-sys; write compact mirror (5 u32/cand); barrier.
//  4. CUTOFF = max over 128 wave-slots of 16th-best key (each wave
//     redundantly reads all 128 rank-15 keys from the mirror + DPP).
//  5. PRUNE: keys > cutk -> u16 index pool (ballot offsets + 1 LDS
//     atomic/wave, r12 pattern; 8 cands/thread). m <= 128*15 = 1920.
//  6. SIM: wave-register tiers NC=8/14/22/30, no barriers; t=0 always
//     commits (global max = someone's exact top-1, in pool); t>=1 iff
//     winner dist STRICTLY > cutoff dist. j >= 1 always.
//  7. COMMIT: rank0 wave0 writes rows S+1..S+j; all blocks min-update
//     register dists per winner, ascending (reference fp order =>
//     bit-exact).
//
// Ring safety (RING=2): a wave ships round r+1 (overwriting slot r-1)
// only after its block's mirror barrier of round r, which requires all
// 4 waves' quarter-polls of r, which require ALL 128 wave-slots stored
// r, each after that wave's poll(r-1) finished reading slot r-1. Tags
// embed r; zeroed/stale slots never match (1 <= r <= 4095 < 2^15).

#define NB    32
#define TPB   256
#define PPT   16
#define NPB   131072
#define MSAMP 4096
#define RING  2
#define KW    16                // candidates per wave
#define NWAVE 128               // waves per batch
#define NQUAD (NWAVE * 32)      // 4096 quads per round per batch
#define RB_U32 (NQUAD * 4)      // 16384 u32 = 64KB per ring slot
#define NCAND (NWAVE * KW)      // 2048
#define JCAP  64

typedef unsigned long long u64;
typedef unsigned int u32;
typedef unsigned short u16;
typedef __attribute__((ext_vector_type(4))) u32 u32x4;

__device__ __forceinline__ void st16_sys(u32* p, u32x4 v) {
  asm volatile("global_store_dwordx4 %0, %1, off sc0 sc1"
               :: "v"(p), "v"(v) : "memory");
}
// 16 poll loads issued back-to-back, ONE vmcnt drain (single RT).
__device__ __forceinline__ void ld16x16_sys(
    const u32* const* p, u32x4* q) {
  asm volatile(
    "global_load_dwordx4 %0, %16, off sc0 sc1\n\t"
    "global_load_dwordx4 %1, %17, off sc0 sc1\n\t"
    "global_load_dwordx4 %2, %18, off sc0 sc1\n\t"
    "global_load_dwordx4 %3, %19, off sc0 sc1\n\t"
    "global_load_dwordx4 %4, %20, off sc0 sc1\n\t"
    "global_load_dwordx4 %5, %21, off sc0 sc1\n\t"
    "global_load_dwordx4 %6, %22, off sc0 sc1\n\t"
    "global_load_dwordx4 %7, %23, off sc0 sc1\n\t"
    "global_load_dwordx4 %8, %24, off sc0 sc1\n\t"
    "global_load_dwordx4 %9, %25, off sc0 sc1\n\t"
    "global_load_dwordx4 %10, %26, off sc0 sc1\n\t"
    "global_load_dwordx4 %11, %27, off sc0 sc1\n\t"
    "global_load_dwordx4 %12, %28, off sc0 sc1\n\t"
    "global_load_dwordx4 %13, %29, off sc0 sc1\n\t"
    "global_load_dwordx4 %14, %30, off sc0 sc1\n\t"
    "global_load_dwordx4 %15, %31, off sc0 sc1\n\t"
    "s_waitcnt vmcnt(0)"
    : "=v"(q[0]), "=v"(q[1]), "=v"(q[2]), "=v"(q[3]),
      "=v"(q[4]), "=v"(q[5]), "=v"(q[6]), "=v"(q[7]),
      "=v"(q[8]), "=v"(q[9]), "=v"(q[10]), "=v"(q[11]),
      "=v"(q[12]), "=v"(q[13]), "=v"(q[14]), "=v"(q[15])
    : "v"(p[0]), "v"(p[1]), "v"(p[2]), "v"(p[3]),
      "v"(p[4]), "v"(p[5]), "v"(p[6]), "v"(p[7]),
      "v"(p[8]), "v"(p[9]), "v"(p[10]), "v"(p[11]),
      "v"(p[12]), "v"(p[13]), "v"(p[14]), "v"(p[15])
    : "memory");
}

// ---- DPP helpers (proven r2-r12) ---------------------------------------
template<int CTRL>
__device__ __forceinline__ u64 dpp_move64(u64 x) {
  int lo = (int)(u32)(x & 0xFFFFFFFFull);
  int hi = (int)(u32)(x >> 32);
  int nlo = __builtin_amdgcn_update_dpp(lo, lo, CTRL, 0xF, 0xF, false);
  int nhi = __builtin_amdgcn_update_dpp(hi, hi, CTRL, 0xF, 0xF, false);
  return ((u64)(u32)nhi << 32) | (u64)(u32)nlo;
}
#define DPP_ROW_SHR(n)  (0x110 + (n))
#define DPP_BCAST15     0x142
#define DPP_BCAST31     0x143

__device__ __forceinline__ u64 dpp_max64_to63(u64 k) {
  u64 t;
  t = dpp_move64<DPP_ROW_SHR(1)>(k); if (t > k) k = t;
  t = dpp_move64<DPP_ROW_SHR(2)>(k); if (t > k) k = t;
  t = dpp_move64<DPP_ROW_SHR(4)>(k); if (t > k) k = t;
  t = dpp_move64<DPP_ROW_SHR(8)>(k); if (t > k) k = t;
  t = dpp_move64<DPP_BCAST15>(k);    if (t > k) k = t;
  t = dpp_move64<DPP_BCAST31>(k);    if (t > k) k = t;
  return k;                                   // lane63 = wave max
}
__device__ __forceinline__ u64 bcast_key(u64 k, int srclane) {
  u32 lo = (u32)__builtin_amdgcn_readlane((int)(u32)(k & 0xFFFFFFFFull), srclane);
  u32 hi = (u32)__builtin_amdgcn_readlane((int)(u32)(k >> 32), srclane);
  return ((u64)hi << 32) | (u64)lo;
}
__device__ __forceinline__ float bcast_f32(float v, int srclane) {
  return __uint_as_float((u32)__builtin_amdgcn_readlane((int)__float_as_uint(v), srclane));
}

// ---- pruned in-register sim, NO barriers, identical on all waves ------
// (r12 verbatim except the u16-index indirection into the compact mirror)
template<int NC>
__device__ __forceinline__ int sim_wave(const u32* s_mir, const u16* s_pidx,
    int m, u32 cutd, int jmax, int lane, float& ox, float& oy, float& oz) {
#pragma clang fp contract(off)
  u64 ck[NC]; float cx[NC], cy[NC], cz[NC];
#pragma unroll
  for (int i = 0; i < NC; ++i) {
    int idx = lane + i * 64;
    if (idx < m) {
      const u32* b = s_mir + (int)s_pidx[idx] * 5;
      ck[i] = ((u64)b[1] << 32) | (u64)b[0];
      cx[i] = __uint_as_float(b[2]); cy[i] = __uint_as_float(b[3]);
      cz[i] = __uint_as_float(b[4]);
    } else { ck[i] = 0; cx[i] = cy[i] = cz[i] = 0.f; }
  }
  int j = 0;
  for (int t = 0; t < jmax; ++t) {
    u64 tk = ck[0]; float mx = cx[0], my = cy[0], mz = cz[0];
#pragma unroll
    for (int i = 1; i < NC; ++i)
      if (ck[i] > tk) { tk = ck[i]; mx = cx[i]; my = cy[i]; mz = cz[i]; }
    u64 wk = bcast_key(dpp_max64_to63(tk), 63);
    if (t > 0 && (u32)(wk >> 32) <= cutd) break;   // not certified: stop
    int wl = __ffsll(__ballot(tk == wk)) - 1;
    float wx = bcast_f32(mx, wl), wy = bcast_f32(my, wl), wz = bcast_f32(mz, wl);
    if (lane == t) { ox = wx; oy = wy; oz = wz; }  // stash winner t
    j = t + 1;
#pragma unroll
    for (int i = 0; i < NC; ++i) {
      float dx = cx[i]-wx, dy = cy[i]-wy, dz = cz[i]-wz;
      float d2 = __fadd_rn(__fadd_rn(__fmul_rn(dx,dx), __fmul_rn(dy,dy)),
                           __fmul_rn(dz,dz));
      float nd = fminf(__uint_as_float((u32)(ck[i] >> 32)), d2);
      ck[i] = ((u64)__float_as_uint(nd) << 32) | (ck[i] & 0xFFFFFFFFull);
    }
  }
  return j;
}

__global__ __launch_bounds__(TPB, 1)
void fps_kernel(const float4* __restrict__ pts, float* __restrict__ out,
                u32* __restrict__ slots)
{
#pragma clang fp contract(off)
  const int batch = blockIdx.x >> 5;
  const int rank  = blockIdx.x & (NB - 1);
  const int tid   = threadIdx.x;
  const int lane  = tid & 63;
  const int wv    = tid >> 6;
  const int ws_id = rank * 4 + wv;           // wave-slot 0..127

  __shared__ u32   s_mir[NCAND * 5];         // compact mirror, 40 KB
  __shared__ u16   s_pidx[NCAND];            // index pool, 4 KB
  __shared__ int   s_cnt2[2];                // ping-pong compact counters

  const float4* bpts = pts + (size_t)batch * NPB;
  u32* bslots = slots + (size_t)batch * (RING * RB_U32);
  const int base = rank * (TPB * PPT);

  float px[PPT], py[PPT], pz[PPT], dist[PPT];
  float4 seed = bpts[0];
  const float sx = seed.y, sy = seed.z, sz = seed.w;
#pragma unroll
  for (int k = 0; k < PPT; ++k) {
    float4 p = bpts[base + k * TPB + tid];   // row = (b, x, y, z)
    px[k] = p.y; py[k] = p.z; pz[k] = p.w;
    float dx = px[k]-sx, dy = py[k]-sy, dz = pz[k]-sz;
    dist[k] = __fadd_rn(__fadd_rn(__fmul_rn(dx,dx), __fmul_rn(dy,dy)),
                        __fmul_rn(dz,dz));   // == reference dist init
  }
  if (rank == 0 && tid == 0) {
    float4 o; o.x=(float)batch; o.y=sx; o.z=sy; o.w=sz;
    *(float4*)(out + (size_t)batch * MSAMP * 4) = o;
  }
  if (tid == 0) { s_cnt2[0] = 0; s_cnt2[1] = 0; }
  __syncthreads();

  int S = 0; u32 r = 0;
  float ox = 0.f, oy = 0.f, oz = 0.f;

  while (S < MSAMP - 1) {
    r += 1;
    const int rem = (MSAMP - 1) - S;
    const int jmax = (rem < JCAP) ? rem : JCAP;

    // ---- EXTRACT: wave top-16, pure DPP, no barriers (r12 loop, c<16) ----
    u32 mask = 0; u64 tk = 0; float tx=0.f, ty=0.f, tz=0.f; int tbk = 0;
#pragma unroll
    for (int k = 0; k < PPT; ++k) {
      u64 kk = ((u64)__float_as_uint(dist[k]) << 32) | ((u64)r << 17) |
               (u64)(0x1FFFF - (base + k * TPB + tid));
      if (kk > tk) { tk = kk; tx = px[k]; ty = py[k]; tz = pz[k]; tbk = k; }
    }
    u32x4 shipq;
    for (int c = 0; c < KW; ++c) {
      u64 wk = bcast_key(dpp_max64_to63(tk), 63);
      int wl = __ffsll(__ballot(tk == wk)) - 1;
      float wx = bcast_f32(tx, wl), wy = bcast_f32(ty, wl), wz = bcast_f32(tz, wl);
      if (lane == 2*c)     { shipq.x=(u32)(wk & 0xFFFFFFFFull); shipq.y=(u32)(wk>>32);
                             shipq.z=__float_as_uint(wx); shipq.w=__float_as_uint(wy); }
      if (lane == 2*c + 1) { shipq.x=r; shipq.y=__float_as_uint(wz);
                             shipq.z=0u; shipq.w=0u; }
      if (tk == wk) {                        // my point won: mask + rescan
        mask |= 1u << tbk;
        tk = 0; tx = ty = tz = 0.f; tbk = 0;
#pragma unroll
        for (int k = 0; k < PPT; ++k) {
          if (!((mask >> k) & 1u)) {
            u64 kk = ((u64)__float_as_uint(dist[k]) << 32) | ((u64)r << 17) |
                     (u64)(0x1FFFF - (base + k * TPB + tid));
            if (kk > tk) { tk = kk; tx = px[k]; ty = py[k]; tz = pz[k]; tbk = k; }
          }
        }
      }
    }

    // ---- SHIP: lanes 0..31 store 16B each (cand C = ws_id*16 + lane/2) ----
    u32* ring = bslots + (size_t)(r & (RING - 1)) * RB_U32;
    if (lane < 32)
      st16_sys(ring + ((ws_id * 16 + (lane >> 1)) * 8 + (lane & 1) * 4), shipq);

    // ---- POLL: my wave's 1024-quad quarter, 16 loads/lane, one RT ----
    const int gb = wv * 1024 + lane;
    const u32* pp[16]; u32x4 q[16];
#pragma unroll
    for (int i = 0; i < 16; ++i) pp[i] = ring + (size_t)(gb + 64 * i) * 4;
    for (;;) {
      ld16x16_sys(pp, q);
      bool ok;
      if ((lane & 1) == 0) {
        ok = true;
#pragma unroll
        for (int i = 0; i < 16; ++i) ok = ok && ((q[i].x >> 17) == r);
      } else {
        ok = true;
#pragma unroll
        for (int i = 0; i < 16; ++i) ok = ok && (q[i].x == r);
      }
      if (__ballot(ok) == ~0ull) break;
      __builtin_amdgcn_s_sleep(1);
    }
    // reset NEXT round's compact counter (safe: ordered by mirror barriers)
    if (tid == 0) s_cnt2[(r + 1) & 1] = 0;
    // compact mirror: even lane writes quad0 fields, odd lane writes z
    {
#pragma unroll
      for (int i = 0; i < 16; ++i) {
        int C = (gb + 64 * i) >> 1;          // cand index, pair-shared
        u32* d = &s_mir[C * 5];
        if ((lane & 1) == 0) { d[0]=q[i].x; d[1]=q[i].y; d[2]=q[i].z; d[3]=q[i].w; }
        else                 { d[4]=q[i].y; }
      }
    }
    __syncthreads();                         // barrier 1: mirror complete

    // ---- CUTOFF: max over 128 wave-16th keys (per wave, no barrier) ----
    u64 cutk;
    {
      int c0 = lane * 16 + 15, c1 = (lane + 64) * 16 + 15;
      u64 k0 = ((u64)s_mir[c0*5 + 1] << 32) | (u64)s_mir[c0*5];
      u64 k1 = ((u64)s_mir[c1*5 + 1] << 32) | (u64)s_mir[c1*5];
      u64 ct = (k0 > k1) ? k0 : k1;
      cutk = bcast_key(dpp_max64_to63(ct), 63);
    }
    const u32 cutd = (u32)(cutk >> 32);

    // ---- PRUNE: wave-aggregated (ballot offsets + 1 atomic/wave) ----
    int* cnt = &s_cnt2[r & 1];
    bool hh[8]; int myoff[8]; int tot = 0;
    const u64 ltmask = (1ull << lane) - 1ull;
#pragma unroll
    for (int i = 0; i < 8; ++i) {
      int cg = tid * 8 + i;
      u64 kk = ((u64)s_mir[cg*5 + 1] << 32) | (u64)s_mir[cg*5];
      hh[i] = kk > cutk;
      u64 b = __ballot(hh[i]);
      myoff[i] = tot + __popcll(b & ltmask);
      tot += __popcll(b);
    }
    int pbase = 0;
    if (lane == 0) pbase = atomicAdd(cnt, tot);
    pbase = __builtin_amdgcn_readfirstlane(pbase);
#pragma unroll
    for (int i = 0; i < 8; ++i)
      if (hh[i]) s_pidx[pbase + myoff[i]] = (u16)(tid * 8 + i);
    __syncthreads();                         // barrier 2: pool + m final
    const int m = *cnt;                      // m <= 128*15 = 1920 (proven)

    // ---- SIM: wave-register tiers only (NC=30 covers 1920) ----
    int j;
    if      (m <= 512)  j = sim_wave<8> (s_mir, s_pidx, m, cutd, jmax, lane, ox, oy, oz);
    else if (m <= 896)  j = sim_wave<14>(s_mir, s_pidx, m, cutd, jmax, lane, ox, oy, oz);
    else if (m <= 1408) j = sim_wave<22>(s_mir, s_pidx, m, cutd, jmax, lane, ox, oy, oz);
    else                j = sim_wave<30>(s_mir, s_pidx, m, cutd, jmax, lane, ox, oy, oz);

    // ---- COMMIT: output rows + batched register dist update ----
    if (rank == 0 && wv == 0 && lane < j) {
      float4 o; o.x = (float)batch; o.y = ox; o.z = oy; o.w = oz;
      *(float4*)(out + (size_t)(batch * MSAMP + S + 1 + lane) * 4) = o;
    }
    for (int i = 0; i < j; ++i) {            // ascending = reference order
      float wx = bcast_f32(ox, i), wy = bcast_f32(oy, i), wz = bcast_f32(oz, i);
#pragma unroll
      for (int k = 0; k < PPT; ++k) {
        float dx = px[k]-wx, dy = py[k]-wy, dz = pz[k]-wz;
        float d2 = __fadd_rn(__fadd_rn(__fmul_rn(dx,dx), __fmul_rn(dy,dy)),
                             __fmul_rn(dz,dz));
        dist[k] = fminf(dist[k], d2);
      }
    }
    S += j;
  }
}

extern "C" void kernel_launch(void* const* d_in, const int* in_sizes, int n_in,
                              void* d_out, int out_size, void* d_ws, size_t ws_size,
                              hipStream_t stream) {
  const float4* pts = (const float4*)d_in[0];
  float* out = (float*)d_out;
  u32* slots = (u32*)d_ws;

  // Zero both batches' rings (256 KB): stale tags can never validate.
  hipMemsetAsync(d_ws, 0, (size_t)2 * RING * RB_U32 * 4, stream);

  dim3 grid(2 * NB), block(TPB);
  hipLaunchKernelGGL(fps_kernel, grid, block, 0, stream, pts, out, slots);
}

// Round 14
// 5901.656 us; speedup vs baseline: 1.0190x; 1.0190x over previous
//
#include <hip/hip_runtime.h>

// FPS: 2 batches x 131072 pts, 4096 samples/batch, seed = point 0.
// EXACT certified lookahead FPS, v9 = r12 structure at KW=16 with a
// KEY-ONLY, pair-packed rendezvous and conflict-free LDS layout.
//
// r13 post-mortem: KW=16 with a 5-u32-stride mirror exploded LDS bank
// conflicts (1.25e6 -> 3.2e7) and VGPR (160->248) -> 6014us. That
// measured the layout, not the depth. v9 keeps KW=16 but:
//  * 2 cands per 16B quad {keyloA,keyhiA,keyloB,keyhiB}; both keylo
//    fields carry the tag (bits 17-31 == r) => self-validating. 1024
//    quads (HALF of r12's poll bytes at DOUBLE the depth).
//  * mirror = u64[2048] (16 KB, stride-8, b128 writes, conflict-free);
//    prune reads cg = i*256+tid (consecutive b64, 2-way = free).
//  * pool = u16 indices (r13-proven); sim gathers coords ONCE per round
//    from L2-resident bpts[idx] (2MB/batch), not per step (r10's cost).
//  * cutoff read from poll registers (r9-proven): lanes lane&7==7 hold
//    rank-15 keyBs of their 4 quads.
// All other code paths r12 verbatim (extraction rescans minus coord
// tracking, ship/poll skeleton, 2 barriers, cert, commit, update).
//
// Key = dist_bits<<32 | r<<17 | (0x1FFFF - idx): u64 order ==
// (dist desc, idx asc) == jnp.argmax first-index tiebreak.
// Cutoff = max over 128 wave-slots of 16th-best key; any unshipped
// point of wave w has key < its wave's rank-15 <= cutk. t=0 always
// certifies (global max = someone's exact top-1, in pool, > cutk by
// uniqueness) => j >= 1, no livelock. t>=1 iff winner dist > cutd.
//
// Ring safety (RING=2): a wave ships round r+1 (overwriting slot r-1)
// only after its block's barrier-1 of round r, which requires all 4
// waves' quarter-polls of r, which require ALL 128 wave-slots stored r,
// each after that wave's poll(r-1) finished reading slot r-1. Tags
// embed r; zeroed/stale slots never match (1 <= r <= 4095 < 2^15).

#define NB    32
#define TPB   256
#define PPT   16
#define NPB   131072
#define MSAMP 4096
#define RING  2
#define KW    16                // candidates per wave
#define NWAVE 128               // waves per batch
#define NCAND (NWAVE * KW)      // 2048 candidates / round / batch
#define NQUAD (NCAND / 2)       // 1024 pair-packed quads
#define RB_U32 (NQUAD * 4)      // 4096 u32 = 16KB per ring slot
#define JCAP  64

typedef unsigned long long u64;
typedef unsigned int u32;
typedef unsigned short u16;
typedef __attribute__((ext_vector_type(4))) u32 u32x4;

__device__ __forceinline__ void st16_sys(u32* p, u32x4 v) {
  asm volatile("global_store_dwordx4 %0, %1, off sc0 sc1"
               :: "v"(p), "v"(v) : "memory");
}
// 4 poll loads issued back-to-back, ONE vmcnt drain (r8/r9-proven).
__device__ __forceinline__ void ld16x4_sys(
    const u32* p0, const u32* p1, const u32* p2, const u32* p3,
    u32x4& q0, u32x4& q1, u32x4& q2, u32x4& q3) {
  asm volatile(
    "global_load_dwordx4 %0, %4, off sc0 sc1\n\t"
    "global_load_dwordx4 %1, %5, off sc0 sc1\n\t"
    "global_load_dwordx4 %2, %6, off sc0 sc1\n\t"
    "global_load_dwordx4 %3, %7, off sc0 sc1\n\t"
    "s_waitcnt vmcnt(0)"
    : "=v"(q0), "=v"(q1), "=v"(q2), "=v"(q3)
    : "v"(p0), "v"(p1), "v"(p2), "v"(p3)
    : "memory");
}

// ---- DPP helpers (proven r2-r13) ---------------------------------------
template<int CTRL>
__device__ __forceinline__ u64 dpp_move64(u64 x) {
  int lo = (int)(u32)(x & 0xFFFFFFFFull);
  int hi = (int)(u32)(x >> 32);
  int nlo = __builtin_amdgcn_update_dpp(lo, lo, CTRL, 0xF, 0xF, false);
  int nhi = __builtin_amdgcn_update_dpp(hi, hi, CTRL, 0xF, 0xF, false);
  return ((u64)(u32)nhi << 32) | (u64)(u32)nlo;
}
#define DPP_ROW_SHR(n)  (0x110 + (n))
#define DPP_BCAST15     0x142
#define DPP_BCAST31     0x143

__device__ __forceinline__ u64 dpp_max64_to63(u64 k) {
  u64 t;
  t = dpp_move64<DPP_ROW_SHR(1)>(k); if (t > k) k = t;
  t = dpp_move64<DPP_ROW_SHR(2)>(k); if (t > k) k = t;
  t = dpp_move64<DPP_ROW_SHR(4)>(k); if (t > k) k = t;
  t = dpp_move64<DPP_ROW_SHR(8)>(k); if (t > k) k = t;
  t = dpp_move64<DPP_BCAST15>(k);    if (t > k) k = t;
  t = dpp_move64<DPP_BCAST31>(k);    if (t > k) k = t;
  return k;                                   // lane63 = wave max
}
__device__ __forceinline__ u64 bcast_key(u64 k, int srclane) {
  u32 lo = (u32)__builtin_amdgcn_readlane((int)(u32)(k & 0xFFFFFFFFull), srclane);
  u32 hi = (u32)__builtin_amdgcn_readlane((int)(u32)(k >> 32), srclane);
  return ((u64)hi << 32) | (u64)lo;
}
__device__ __forceinline__ float bcast_f32(float v, int srclane) {
  return __uint_as_float((u32)__builtin_amdgcn_readlane((int)__float_as_uint(v), srclane));
}

// ---- pruned in-register sim, NO barriers (r12 verbatim except init:
// key via u16 index -> u64 mirror; coords gathered once from bpts) ----
template<int NC>
__device__ __forceinline__ int sim_wave(const u64* s_mir, const u16* s_pidx,
    const float4* __restrict__ bpts, int m, u32 cutd, int jmax, int lane,
    float& ox, float& oy, float& oz) {
#pragma clang fp contract(off)
  u64 ck[NC]; float cx[NC], cy[NC], cz[NC];
#pragma unroll
  for (int i = 0; i < NC; ++i) {
    int idx = lane + i * 64;
    if (idx < m) {
      u64 k = s_mir[s_pidx[idx]];
      int gi = (int)(0x1FFFFu - (u32)(k & 0x1FFFFull));
      float4 c = bpts[gi];
      ck[i] = k; cx[i] = c.y; cy[i] = c.z; cz[i] = c.w;
    } else { ck[i] = 0; cx[i] = cy[i] = cz[i] = 0.f; }
  }
  int j = 0;
  for (int t = 0; t < jmax; ++t) {
    u64 tk = ck[0]; float mx = cx[0], my = cy[0], mz = cz[0];
#pragma unroll
    for (int i = 1; i < NC; ++i)
      if (ck[i] > tk) { tk = ck[i]; mx = cx[i]; my = cy[i]; mz = cz[i]; }
    u64 wk = bcast_key(dpp_max64_to63(tk), 63);
    if (t > 0 && (u32)(wk >> 32) <= cutd) break;   // not certified: stop
    int wl = __ffsll(__ballot(tk == wk)) - 1;
    float wx = bcast_f32(mx, wl), wy = bcast_f32(my, wl), wz = bcast_f32(mz, wl);
    if (lane == t) { ox = wx; oy = wy; oz = wz; }  // stash winner t
    j = t + 1;
#pragma unroll
    for (int i = 0; i < NC; ++i) {
      float dx = cx[i]-wx, dy = cy[i]-wy, dz = cz[i]-wz;
      float d2 = __fadd_rn(__fadd_rn(__fmul_rn(dx,dx), __fmul_rn(dy,dy)),
                           __fmul_rn(dz,dz));
      float nd = fminf(__uint_as_float((u32)(ck[i] >> 32)), d2);
      ck[i] = ((u64)__float_as_uint(nd) << 32) | (ck[i] & 0xFFFFFFFFull);
    }
  }
  return j;
}

__global__ __launch_bounds__(TPB, 1)
void fps_kernel(const float4* __restrict__ pts, float* __restrict__ out,
                u32* __restrict__ slots)
{
#pragma clang fp contract(off)
  const int batch = blockIdx.x >> 5;
  const int rank  = blockIdx.x & (NB - 1);
  const int tid   = threadIdx.x;
  const int lane  = tid & 63;
  const int wv    = tid >> 6;
  const int ws_id = rank * 4 + wv;           // wave-slot 0..127

  __shared__ __attribute__((aligned(16))) u64 s_mir[NCAND];  // 16 KB
  __shared__ u16   s_pidx[NCAND];            // 4 KB index pool
  __shared__ u64   s_cutq[4];
  __shared__ int   s_cnt2[2];                // ping-pong compact counters

  const float4* bpts = pts + (size_t)batch * NPB;
  u32* bslots = slots + (size_t)batch * (RING * RB_U32);
  const int base = rank * (TPB * PPT);

  float px[PPT], py[PPT], pz[PPT], dist[PPT];
  float4 seed = bpts[0];
  const float sx = seed.y, sy = seed.z, sz = seed.w;
#pragma unroll
  for (int k = 0; k < PPT; ++k) {
    float4 p = bpts[base + k * TPB + tid];   // row = (b, x, y, z)
    px[k] = p.y; py[k] = p.z; pz[k] = p.w;
    float dx = px[k]-sx, dy = py[k]-sy, dz = pz[k]-sz;
    dist[k] = __fadd_rn(__fadd_rn(__fmul_rn(dx,dx), __fmul_rn(dy,dy)),
                        __fmul_rn(dz,dz));   // == reference dist init
  }
  if (rank == 0 && tid == 0) {
    float4 o; o.x=(float)batch; o.y=sx; o.z=sy; o.w=sz;
    *(float4*)(out + (size_t)batch * MSAMP * 4) = o;
  }
  if (tid == 0) { s_cnt2[0] = 0; s_cnt2[1] = 0; }
  __syncthreads();

  int S = 0; u32 r = 0;
  float ox = 0.f, oy = 0.f, oz = 0.f;

  while (S < MSAMP - 1) {
    r += 1;
    const int rem = (MSAMP - 1) - S;
    const int jmax = (rem < JCAP) ? rem : JCAP;

    // ---- EXTRACT: wave top-16 keys, r12 rescan loop minus coords ----
    u32 mask = 0; u64 tk = 0; int tbk = 0;
#pragma unroll
    for (int k = 0; k < PPT; ++k) {
      u64 kk = ((u64)__float_as_uint(dist[k]) << 32) | ((u64)r << 17) |
               (u64)(0x1FFFF - (base + k * TPB + tid));
      if (kk > tk) { tk = kk; tbk = k; }
    }
    u32x4 shipq; shipq.x = shipq.y = shipq.z = shipq.w = 0u;
    for (int c = 0; c < KW; ++c) {
      u64 wk = bcast_key(dpp_max64_to63(tk), 63);
      u32 lo = (u32)(wk & 0xFFFFFFFFull), hi = (u32)(wk >> 32);
      if (lane == (c >> 1)) {                // quad Q=c>>1 carries pops 2Q,2Q+1
        if (c & 1) { shipq.z = lo; shipq.w = hi; }
        else       { shipq.x = lo; shipq.y = hi; }
      }
      if (tk == wk) {                        // my point won: mask + rescan
        mask |= 1u << tbk;
        tk = 0; tbk = 0;
#pragma unroll
        for (int k = 0; k < PPT; ++k) {
          if (!((mask >> k) & 1u)) {
            u64 kk = ((u64)__float_as_uint(dist[k]) << 32) | ((u64)r << 17) |
                     (u64)(0x1FFFF - (base + k * TPB + tid));
            if (kk > tk) { tk = kk; tbk = k; }
          }
        }
      }
    }

    // ---- SHIP: lanes 0..7 store one pair-quad each, unacked ----
    u32* ring = bslots + (size_t)(r & (RING - 1)) * RB_U32;
    if (lane < 8) st16_sys(ring + (ws_id * 8 + lane) * 4, shipq);

    // ---- POLL: wave's 256-quad quarter, 4 batched loads/lane ----
    const int gq = wv * 256 + lane;
    const u32 *P0 = ring + (size_t)(gq      ) * 4,
              *P1 = ring + (size_t)(gq +  64) * 4,
              *P2 = ring + (size_t)(gq + 128) * 4,
              *P3 = ring + (size_t)(gq + 192) * 4;
    u32x4 q0, q1, q2, q3;
    for (;;) {
      ld16x4_sys(P0, P1, P2, P3, q0, q1, q2, q3);
      bool ok = ((q0.x>>17)==r) && ((q0.z>>17)==r) &&
                ((q1.x>>17)==r) && ((q1.z>>17)==r) &&
                ((q2.x>>17)==r) && ((q2.z>>17)==r) &&
                ((q3.x>>17)==r) && ((q3.z>>17)==r);
      if (__ballot(ok) == ~0ull) break;
      __builtin_amdgcn_s_sleep(1);
    }
    if (tid == 0) s_cnt2[(r + 1) & 1] = 0;   // reset next round's counter

    // ---- MIRROR: quad g -> s_mir[2g],s_mir[2g+1]; b128, conflict-free ----
    {
      u32* mir32 = (u32*)s_mir;
      *(u32x4*)&mir32[(size_t)(gq      ) * 4] = q0;
      *(u32x4*)&mir32[(size_t)(gq +  64) * 4] = q1;
      *(u32x4*)&mir32[(size_t)(gq + 128) * 4] = q2;
      *(u32x4*)&mir32[(size_t)(gq + 192) * 4] = q3;
    }

    // ---- CUTOFF from poll regs: lanes lane&7==7 hold rank-15 keyBs ----
    u64 cm = 0ull;
    if ((lane & 7) == 7) {                   // gq%8==7 -> keyB = rank-15
      u64 a0 = ((u64)q0.w << 32) | (u64)q0.z;
      u64 a1 = ((u64)q1.w << 32) | (u64)q1.z;
      u64 a2 = ((u64)q2.w << 32) | (u64)q2.z;
      u64 a3 = ((u64)q3.w << 32) | (u64)q3.z;
      cm = a0; if (a1 > cm) cm = a1; if (a2 > cm) cm = a2; if (a3 > cm) cm = a3;
    }
    u64 qc = bcast_key(dpp_max64_to63(cm), 63);
    if (lane == 0) s_cutq[wv] = qc;
    __syncthreads();                         // barrier 1: mirror + cutq
    u64 cutk = s_cutq[0];
    if (s_cutq[1] > cutk) cutk = s_cutq[1];
    if (s_cutq[2] > cutk) cutk = s_cutq[2];
    if (s_cutq[3] > cutk) cutk = s_cutq[3];
    const u32 cutd = (u32)(cutk >> 32);

    // ---- PRUNE: wave-aggregated u16 append (consecutive b64 reads) ----
    int* cnt = &s_cnt2[r & 1];
    bool hh[8]; int myoff[8]; int tot = 0;
    const u64 ltmask = (1ull << lane) - 1ull;
#pragma unroll
    for (int i = 0; i < 8; ++i) {
      int cg = i * 256 + tid;                // lanes consecutive: no conflict
      u64 kk = s_mir[cg];
      hh[i] = kk > cutk;
      u64 b = __ballot(hh[i]);
      myoff[i] = tot + __popcll(b & ltmask);
      tot += __popcll(b);
    }
    int pbase = 0;
    if (lane == 0) pbase = atomicAdd(cnt, tot);
    pbase = __builtin_amdgcn_readfirstlane(pbase);
#pragma unroll
    for (int i = 0; i < 8; ++i)
      if (hh[i]) s_pidx[pbase + myoff[i]] = (u16)(i * 256 + tid);
    __syncthreads();                         // barrier 2: pool + m final
    const int m = *cnt;                      // m <= 128*15 = 1920 (proven)

    // ---- SIM: wave-register tiers (NC=30 covers 1920) ----
    int j;
    if      (m <= 512)  j = sim_wave<8> (s_mir, s_pidx, bpts, m, cutd, jmax, lane, ox, oy, oz);
    else if (m <= 896)  j = sim_wave<14>(s_mir, s_pidx, bpts, m, cutd, jmax, lane, ox, oy, oz);
    else if (m <= 1408) j = sim_wave<22>(s_mir, s_pidx, bpts, m, cutd, jmax, lane, ox, oy, oz);
    else                j = sim_wave<30>(s_mir, s_pidx, bpts, m, cutd, jmax, lane, ox, oy, oz);

    // ---- COMMIT: output rows + batched register dist update ----
    if (rank == 0 && wv == 0 && lane < j) {
      float4 o; o.x = (float)batch; o.y = ox; o.z = oy; o.w = oz;
      *(float4*)(out + (size_t)(batch * MSAMP + S + 1 + lane) * 4) = o;
    }
    for (int i = 0; i < j; ++i) {            // ascending = reference order
      float wx = bcast_f32(ox, i), wy = bcast_f32(oy, i), wz = bcast_f32(oz, i);
#pragma unroll
      for (int k = 0; k < PPT; ++k) {
        float dx = px[k]-wx, dy = py[k]-wy, dz = pz[k]-wz;
        float d2 = __fadd_rn(__fadd_rn(__fmul_rn(dx,dx), __fmul_rn(dy,dy)),
                             __fmul_rn(dz,dz));
        dist[k] = fminf(dist[k], d2);
      }
    }
    S += j;
  }
}

extern "C" void kernel_launch(void* const* d_in, const int* in_sizes, int n_in,
                              void* d_out, int out_size, void* d_ws, size_t ws_size,
                              hipStream_t stream) {
  const float4* pts = (const float4*)d_in[0];
  float* out = (float*)d_out;
  u32* slots = (u32*)d_ws;

  // Zero both batches' rings (64 KB): stale tags can never validate.
  hipMemsetAsync(d_ws, 0, (size_t)2 * RING * RB_U32 * 4, stream);

  dim3 grid(2 * NB), block(TPB);
  hipLaunchKernelGGL(fps_kernel, grid, block, 0, stream, pts, out, slots);
}